// Round 3
// baseline (237.287 us; speedup 1.0000x reference)
//
#include <hip/hip_runtime.h>

// Problem constants
#define BATCH   512
#define LEN     8192
#define NCH     10      // C = n_variates = groups = out_channels
#define BAG     1146
#define STRIDE  286
#define L_OUT   25
#define POOLK   3
#define L_P     8
#define NCLS    10
#define NFEAT   (NCH * L_P)   // 80

// Kernel 1: one block per (b,c) row. Stage row in LDS, compute 25 window sums,
// write neg[bc*25 + o] = -(sum + bias_c)^2 to workspace.
__global__ __launch_bounds__(256) void conv_win_kernel(
    const float* __restrict__ x, const float* __restrict__ conv_bias,
    float* __restrict__ neg_out) {
    const int bc = blockIdx.x;            // b*NCH + c
    const int c  = bc % NCH;

    __shared__ float s[LEN];              // 32 KB

    // coalesced float4 staging: 2048 float4, 256 threads, 8 each
    const float4* row4 = (const float4*)(x + (size_t)bc * LEN);
    float4* s4 = (float4*)s;
#pragma unroll
    for (int i = 0; i < (LEN / 4) / 256; ++i) {
        s4[threadIdx.x + i * 256] = row4[threadIdx.x + i * 256];
    }
    __syncthreads();

    const int wave = threadIdx.x >> 6;
    const int lane = threadIdx.x & 63;
    const float bias = conv_bias[c];

    for (int o = wave; o < L_OUT; o += 4) {
        const int start = o * STRIDE;
        float sum = 0.f;
        // lanes stride the 1146-element window; consecutive lanes hit
        // consecutive LDS banks (2 lanes/bank aliasing = free)
        for (int k = lane; k < BAG; k += 64) sum += s[start + k];
        // 64-lane butterfly reduce
#pragma unroll
        for (int off = 32; off > 0; off >>= 1) sum += __shfl_xor(sum, off);
        if (lane == 0) {
            const float v = sum + bias;
            neg_out[bc * L_OUT + o] = -(v * v);
        }
    }
}

// Kernel 2: one block per batch element. MaxPool(3) -> 80 features -> FC 80->10.
__global__ __launch_bounds__(128) void pool_fc_kernel(
    const float* __restrict__ neg, const float* __restrict__ fc_w,
    const float* __restrict__ fc_b, float* __restrict__ out) {
    const int b = blockIdx.x;
    const int t = threadIdx.x;
    __shared__ float flat[NFEAT];

    if (t < NFEAT) {
        const int c = t >> 3;             // feature f = c*8 + p (reshape order)
        const int p = t & 7;
        const float* n = neg + (size_t)(b * NCH + c) * L_OUT + p * POOLK;
        flat[t] = fmaxf(fmaxf(n[0], n[1]), n[2]);
    }
    __syncthreads();

    if (t < NCLS) {
        float acc = fc_b[t];
#pragma unroll
        for (int f = 0; f < NFEAT; ++f) acc += flat[f] * fc_w[t * NFEAT + f];
        out[b * NCLS + t] = acc;
    }
}

extern "C" void kernel_launch(void* const* d_in, const int* in_sizes, int n_in,
                              void* d_out, int out_size, void* d_ws, size_t ws_size,
                              hipStream_t stream) {
    const float* x         = (const float*)d_in[0];
    const float* conv_bias = (const float*)d_in[1];
    const float* fc_w      = (const float*)d_in[2];
    const float* fc_b      = (const float*)d_in[3];
    float* out = (float*)d_out;
    float* neg = (float*)d_ws;            // needs 512*10*25*4 = 512000 B of ws

    conv_win_kernel<<<BATCH * NCH, 256, 0, stream>>>(x, conv_bias, neg);
    pool_fc_kernel<<<BATCH, 128, 0, stream>>>(neg, fc_w, fc_b, out);
}

// Round 5
// 234.455 us; speedup vs baseline: 1.0121x; 1.0121x over previous
//
#include <hip/hip_runtime.h>

// Problem constants
#define BATCH   512
#define LEN     8192
#define NCH     10      // C = n_variates = groups = out_channels
#define BAG     1146    // == 4*STRIDE + 2
#define STRIDE  286
#define L_OUT   25
#define POOLK   3
#define L_P     8
#define NCLS    10
#define NFEAT   (NCH * L_P)   // 80

// win(o) = S(o)+S(o+1)+S(o+2)+S(o+3) + x[286(o+4)] + x[286(o+4)+1]
// where S(j) = sum of 286 consecutive floats starting at 286*j.
// Segments are disjoint -> every input element read exactly once from HBM.
__global__ __launch_bounds__(256) void seg_win_kernel(
    const float* __restrict__ x, const float* __restrict__ conv_bias,
    float* __restrict__ neg_out) {
    const int bc = blockIdx.x;            // b*NCH + c
    const int c  = bc % NCH;
    const float* row = x + (size_t)bc * LEN;

    __shared__ float S[28];    // segment sums, j = 0..27
    __shared__ float F2[29];   // first-two-element sums, used for j = 4..28

    const int wave = threadIdx.x >> 6;
    const int lane = threadIdx.x & 63;

    // 29 segment slots over 4 waves: wave w takes j = w, w+4, ...
    for (int j = wave; j < 29; j += 4) {
        // byte offset of segment j = 286*j*4 = 1144*j -> always 8-byte aligned
        const float2* p2 = (const float2*)(row + j * STRIDE);
        float2 v0 = make_float2(0.f, 0.f);
        float2 v1 = make_float2(0.f, 0.f);
        float2 v2 = make_float2(0.f, 0.f);
        if (j < 28) {
            v0 = p2[lane];                        // 143 float2 per segment
            v1 = p2[lane + 64];
            if (lane < 15) v2 = p2[lane + 128];
        } else if (lane == 0) {
            v0 = p2[0];                           // j==28: only first-2 needed
        }
        const float f2v = v0.x + v0.y;            // lane 0 holds first-2 sum
        float sum = (v0.x + v0.y) + (v1.x + v1.y) + (v2.x + v2.y);
#pragma unroll
        for (int off = 32; off > 0; off >>= 1) sum += __shfl_xor(sum, off);
        if (lane == 0) {
            if (j < 28) S[j] = sum;
            F2[j] = f2v;
        }
    }
    __syncthreads();

    const int t = threadIdx.x;
    if (t < L_OUT) {
        const float w = S[t] + S[t + 1] + S[t + 2] + S[t + 3] + F2[t + 4]
                        + conv_bias[c];
        neg_out[bc * L_OUT + t] = -(w * w);
    }
}

// Kernel 2: one block per batch element. MaxPool(3) -> 80 features -> FC 80->10.
__global__ __launch_bounds__(128) void pool_fc_kernel(
    const float* __restrict__ neg, const float* __restrict__ fc_w,
    const float* __restrict__ fc_b, float* __restrict__ out) {
    const int b = blockIdx.x;
    const int t = threadIdx.x;
    __shared__ float flat[NFEAT];

    if (t < NFEAT) {
        const int c = t >> 3;             // feature f = c*8 + p (reshape order)
        const int p = t & 7;
        const float* n = neg + (size_t)(b * NCH + c) * L_OUT + p * POOLK;
        flat[t] = fmaxf(fmaxf(n[0], n[1]), n[2]);
    }
    __syncthreads();

    if (t < NCLS) {
        float acc = fc_b[t];
#pragma unroll
        for (int f = 0; f < NFEAT; ++f) acc += flat[f] * fc_w[t * NFEAT + f];
        out[b * NCLS + t] = acc;
    }
}

extern "C" void kernel_launch(void* const* d_in, const int* in_sizes, int n_in,
                              void* d_out, int out_size, void* d_ws, size_t ws_size,
                              hipStream_t stream) {
    const float* x         = (const float*)d_in[0];
    const float* conv_bias = (const float*)d_in[1];
    const float* fc_w      = (const float*)d_in[2];
    const float* fc_b      = (const float*)d_in[3];
    float* out = (float*)d_out;
    float* neg = (float*)d_ws;            // needs 512*10*25*4 = 512000 B of ws

    seg_win_kernel<<<BATCH * NCH, 256, 0, stream>>>(x, conv_bias, neg);
    pool_fc_kernel<<<BATCH, 128, 0, stream>>>(neg, fc_w, fc_b, out);
}

// Round 6
// 233.434 us; speedup vs baseline: 1.0165x; 1.0044x over previous
//
#include <hip/hip_runtime.h>

// Problem constants
#define BATCH   512
#define LEN     8192
#define NCH     10      // C = n_variates = groups = out_channels
#define BAG     1146    // == 4*STRIDE + 2
#define STRIDE  286
#define L_OUT   25
#define POOLK   3
#define L_P     8
#define NCLS    10
#define NFEAT   (NCH * L_P)   // 80

// win(o) = S(o)+S(o+1)+S(o+2)+S(o+3) + x[286(o+4)] + x[286(o+4)+1]
// where S(j) = sum of the disjoint 286-float segment starting at 286*j.
// Every needed input element is read exactly once from HBM.
// Fused: also does the MaxPool(3) for this (b,c) row -> 8 feats.
__global__ __launch_bounds__(256) void seg_pool_kernel(
    const float* __restrict__ x, const float* __restrict__ conv_bias,
    float* __restrict__ feats) {
    const int bc = blockIdx.x;            // b*NCH + c
    const int c  = bc % NCH;
    const int b  = bc / NCH;
    const float* row = x + (size_t)bc * LEN;

    __shared__ float S[28];    // segment sums, j = 0..27
    __shared__ float F2[28];   // first-two-element sums of segment j
    __shared__ float W[L_OUT]; // -(win+bias)^2

    const int wave = threadIdx.x >> 6;
    const int lane = threadIdx.x & 63;

    // 28 segments over 4 waves: wave w takes j = w, w+4, ... (7 each, uniform)
    for (int j = wave; j < 28; j += 4) {
        // byte offset of segment j = 1144*j -> always 8-byte aligned
        const float2* p2 = (const float2*)(row + j * STRIDE);
        const float2 v0 = p2[lane];                      // 143 float2/segment
        const float2 v1 = p2[lane + 64];
        float2 v2 = make_float2(0.f, 0.f);
        if (lane < 15) v2 = p2[lane + 128];
        const float f2v = v0.x + v0.y;                   // lane 0: first-2 sum
        float sum = (v0.x + v0.y) + (v1.x + v1.y) + (v2.x + v2.y);
#pragma unroll
        for (int off = 32; off > 0; off >>= 1) sum += __shfl_xor(sum, off);
        if (lane == 0) { S[j] = sum; F2[j] = f2v; }
    }
    __syncthreads();

    const int t = threadIdx.x;
    if (t < L_OUT) {
        // F2[t+4] valid for t<24; t==24 needs x[8008]+x[8009] (never in a segment)
        const float tail = (t < 24) ? F2[t + 4] : (row[8008] + row[8009]);
        const float w = S[t] + S[t + 1] + S[t + 2] + S[t + 3] + tail
                        + conv_bias[c];
        W[t] = -(w * w);
    }
    __syncthreads();

    if (t < L_P) {  // MaxPool(3): trims element 24
        feats[(size_t)b * NFEAT + c * L_P + t] =
            fmaxf(fmaxf(W[3 * t], W[3 * t + 1]), W[3 * t + 2]);
    }
}

// Kernel 2: wave-only FC 80 -> 10 per batch element.
__global__ __launch_bounds__(64) void fc_kernel(
    const float* __restrict__ feats, const float* __restrict__ fc_w,
    const float* __restrict__ fc_b, float* __restrict__ out) {
    const int b = blockIdx.x;
    const int t = threadIdx.x;
    if (t < NCLS) {
        const float* f = feats + (size_t)b * NFEAT;
        float acc = fc_b[t];
#pragma unroll
        for (int k = 0; k < NFEAT; ++k) acc += f[k] * fc_w[t * NFEAT + k];
        out[b * NCLS + t] = acc;
    }
}

extern "C" void kernel_launch(void* const* d_in, const int* in_sizes, int n_in,
                              void* d_out, int out_size, void* d_ws, size_t ws_size,
                              hipStream_t stream) {
    const float* x         = (const float*)d_in[0];
    const float* conv_bias = (const float*)d_in[1];
    const float* fc_w      = (const float*)d_in[2];
    const float* fc_b      = (const float*)d_in[3];
    float* out   = (float*)d_out;
    float* feats = (float*)d_ws;          // 512*80*4 = 163840 B of ws

    seg_pool_kernel<<<BATCH * NCH, 256, 0, stream>>>(x, conv_bias, feats);
    fc_kernel<<<BATCH, 64, 0, stream>>>(feats, fc_w, fc_b, out);
}